// Round 22
// baseline (139.010 us; speedup 1.0000x reference)
//
#include <hip/hip_runtime.h>

constexpr int N56 = 56*56*64;    // 200704
constexpr int N28 = 28*28*128;   // 100352
constexpr int N14 = 14*14*256;   //  50176
constexpr int N7  = 7*7*512;     //  25088
constexpr int NTOT = N56 + N28 + N14 + N7;       // 376320
constexpr int CONV_BLOCKS = (NTOT + 255) / 256;  // 1470

typedef float    f4v __attribute__((ext_vector_type(4)));
typedef _Float16 h4v __attribute__((ext_vector_type(4)));

// ---- fp32 features -> fp16 in d_ws ----
__global__ __launch_bounds__(256) void convert_feats_kernel(
    const float* __restrict__ f56, const float* __restrict__ f28,
    const float* __restrict__ f14, const float* __restrict__ f7,
    _Float16* __restrict__ ws)
{
    int idx = blockIdx.x * 256 + threadIdx.x;
    if (idx >= NTOT) return;
    float v;
    if (idx < N56)              v = f56[idx];
    else if (idx < N56+N28)     v = f28[idx - N56];
    else if (idx < N56+N28+N14) v = f14[idx - (N56+N28)];
    else                        v = f7[idx - (N56+N28+N14)];
    ws[idx] = (_Float16)v;
}

// ---- hot kernel: ONE POINT PER WAVE, zero barriers.
// Each wave computes its point's 963-float row into a private LDS slice
// (wave-local ds ops; lgkmcnt(0) is the only sync), then flushes it as a
// mostly-16B-aligned nt burst. Overlap comes from 32 independent
// wave-pipelines per CU. Bilinear params are wave-uniform -> SGPRs. ----
__global__ __launch_bounds__(256) void GraphProjection_57483842289710_kernel(
    const float* __restrict__ coord,
    const _Float16* __restrict__ ws,
    float* __restrict__ out, int n)
{
    __shared__ float lds[4 * 963];   // 15408 B -> 8 blocks/CU (max occupancy)
    const int wave = threadIdx.x >> 6;
    const int lane = threadIdx.x & 63;
    const int p = blockIdx.x * 4 + wave;
    if (p >= n) return;             // wave-uniform; no barriers in kernel
    float* __restrict__ myrow = lds + wave * 963;

    const float X = coord[p * 3 + 0];
    const float Y = coord[p * 3 + 1];
    const float Z = coord[p * 3 + 2];
    const float rz = 1.0f / (-Z);
    float h = 250.0f * (-Y) * rz + 112.0f;
    float w = 250.0f * X  * rz + 112.0f;
    h = fminf(fmaxf(h, 0.0f), 223.0f);
    w = fminf(fmaxf(w, 0.0f), 223.0f);

    // Per-level setup -> named uniform scalars; offsets readfirstlane'd to
    // SGPR (provably uniform: computed from wave-uniform coord values).
#define SETUP(L, INV, HH, CC)                                                  \
    int L##o11, L##o21, L##o12, L##o22;                                        \
    float L##w11, L##w21, L##w12, L##w22;                                      \
    {                                                                          \
        const float x = h * (INV), y = w * (INV);                              \
        const float x1 = floorf(x), x2 = ceilf(x);                             \
        const float y1 = floorf(y), y2 = ceilf(y);                             \
        const int xi1 = min(max((int)x1, 0), (HH) - 1);                        \
        const int xi2 = min(max((int)x2, 0), (HH) - 1);                        \
        const int yi1 = min(max((int)y1, 0), (HH) - 1);                        \
        const int yi2 = min(max((int)y2, 0), (HH) - 1);                        \
        L##o11 = __builtin_amdgcn_readfirstlane((xi1 * (HH) + yi1) * (CC));    \
        L##o21 = __builtin_amdgcn_readfirstlane((xi2 * (HH) + yi1) * (CC));    \
        L##o12 = __builtin_amdgcn_readfirstlane((xi1 * (HH) + yi2) * (CC));    \
        L##o22 = __builtin_amdgcn_readfirstlane((xi2 * (HH) + yi2) * (CC));    \
        L##w11 = (x2 - x) * (y2 - y);                                          \
        L##w21 = (x - x1) * (y2 - y);                                          \
        L##w12 = (x2 - x) * (y - y1);                                          \
        L##w22 = (x - x1) * (y - y1);                                          \
    }
    SETUP(l0, 0.25f,    56, 64)
    SETUP(l1, 0.125f,   28, 128)
    SETUP(l2, 0.0625f,  14, 256)
    SETUP(l3, 0.03125f,  7, 512)

#define GATHER(L, FB, CH, DCH)                                                 \
    {                                                                          \
        const _Float16* fp = (FB) + (DCH);                                     \
        const h4v a = *reinterpret_cast<const h4v*>(fp + L##o11);              \
        const h4v b = *reinterpret_cast<const h4v*>(fp + L##o21);              \
        const h4v d = *reinterpret_cast<const h4v*>(fp + L##o12);              \
        const h4v e = *reinterpret_cast<const h4v*>(fp + L##o22);              \
        float* dst = myrow + 3 + (CH);                                         \
        dst[0] = L##w11*(float)a.x + L##w21*(float)b.x + L##w12*(float)d.x + L##w22*(float)e.x; \
        dst[1] = L##w11*(float)a.y + L##w21*(float)b.y + L##w12*(float)d.y + L##w22*(float)e.y; \
        dst[2] = L##w11*(float)a.z + L##w21*(float)b.z + L##w12*(float)d.z + L##w22*(float)e.z; \
        dst[3] = L##w11*(float)a.w + L##w21*(float)b.w + L##w12*(float)d.w + L##w22*(float)e.w; \
    }

    // 240 channel-quads over 4 passes of 64 lanes.
    {   // pass 1: q = lane (0..63) -> L0 / L1 / L2 (exec-masked 3-way)
        const int q = lane, ch = 4 * q;
        if (q < 16)      GATHER(l0, ws,             ch, ch)
        else if (q < 48) GATHER(l1, ws + N56,       ch, ch - 64)
        else             GATHER(l2, ws + N56 + N28, ch, ch - 192)
    }
    {   // pass 2: q = 64+lane (64..127) -> L2 / L3
        const int q = 64 + lane, ch = 4 * q;
        if (q < 112) GATHER(l2, ws + N56 + N28,       ch, ch - 192)
        else         GATHER(l3, ws + N56 + N28 + N14, ch, ch - 448)
    }
    {   // pass 3: q = 128+lane (128..191) -> all L3
        const int q = 128 + lane, ch = 4 * q;
        GATHER(l3, ws + N56 + N28 + N14, ch, ch - 448)
    }
    {   // pass 4: q = 192+lane (192..239) -> L3, 48 active lanes
        const int q = 192 + lane, ch = 4 * q;
        if (q < 240) GATHER(l3, ws + N56 + N28 + N14, ch, ch - 448)
    }
    if (lane < 3) myrow[lane] = coord[p * 3 + lane];

    // wave-local LDS drain; no block barrier anywhere
    asm volatile("s_waitcnt lgkmcnt(0)" ::: "memory");
    __builtin_amdgcn_sched_barrier(0);

    // flush own row: head (<=3 scalars) + 240 aligned nt f4 + tail (<=3)
    const size_t s = (size_t)p * 963;
    const int k0 = p & 3;            // (963p + k0) % 4 == 0 -> 16B-aligned body
    if (lane < k0)
        __builtin_nontemporal_store(myrow[lane], out + s + lane);
    #pragma unroll
    for (int j = 0; j < 4; ++j) {
        const int i = lane + 64 * j;
        if (i < 240) {
            const float* src = myrow + k0 + 4 * i;
            f4v v; v.x = src[0]; v.y = src[1]; v.z = src[2]; v.w = src[3];
            __builtin_nontemporal_store(v,
                reinterpret_cast<f4v*>(out + s + k0 + 4 * i));
        }
    }
    if (lane < 3 - k0) {
        const int idx = k0 + 960 + lane;
        __builtin_nontemporal_store(myrow[idx], out + s + idx);
    }
}

// ---- fp32 fallback (round-4 winner) if ws too small ----
__global__ __launch_bounds__(256) void proj_f32_kernel(
    const float* __restrict__ coord,
    const float* __restrict__ f56, const float* __restrict__ f28,
    const float* __restrict__ f14, const float* __restrict__ f7,
    float* __restrict__ out, int n)
{
    const int t = threadIdx.x;
    const int ch = 4 * t;
    const float* f; int C, H; float inv;
    if (ch < 64)       { f = f56 + ch;         C = 64;  H = 56; inv = 0.25f;    }
    else if (ch < 192) { f = f28 + (ch - 64);  C = 128; H = 28; inv = 0.125f;   }
    else if (ch < 448) { f = f14 + (ch - 192); C = 256; H = 14; inv = 0.0625f;  }
    else               { f = f7  + (ch - 448); C = 512; H = 7;  inv = 0.03125f; }
    const int p0 = blockIdx.x * 16, pend = min(p0 + 16, n);
    #pragma unroll 2
    for (int p = p0; p < pend; ++p) {
        float* __restrict__ orow = out + (size_t)p * 963;
        const float X = coord[p*3+0], Y = coord[p*3+1], Z = coord[p*3+2];
        const float rz = 1.0f / (-Z);
        float h = 250.0f * (-Y) * rz + 112.0f;
        float w = 250.0f * X  * rz + 112.0f;
        h = fminf(fmaxf(h, 0.0f), 223.0f);
        w = fminf(fmaxf(w, 0.0f), 223.0f);
        if (t < 240) {
            const float x = h * inv, y = w * inv;
            const float x1 = floorf(x), x2 = ceilf(x);
            const float y1 = floorf(y), y2 = ceilf(y);
            const int xi1 = min(max((int)x1, 0), H - 1);
            const int xi2 = min(max((int)x2, 0), H - 1);
            const int yi1 = min(max((int)y1, 0), H - 1);
            const int yi2 = min(max((int)y2, 0), H - 1);
            const float w11 = (x2-x)*(y2-y), w21 = (x-x1)*(y2-y);
            const float w12 = (x2-x)*(y-y1), w22 = (x-x1)*(y-y1);
            const int r1 = xi1*H, r2 = xi2*H;
            const float4 a = *reinterpret_cast<const float4*>(f + (r1+yi1)*C);
            const float4 b = *reinterpret_cast<const float4*>(f + (r2+yi1)*C);
            const float4 d = *reinterpret_cast<const float4*>(f + (r1+yi2)*C);
            const float4 e = *reinterpret_cast<const float4*>(f + (r2+yi2)*C);
            f4v r;
            r.x = w11*a.x + w21*b.x + w12*d.x + w22*e.x;
            r.y = w11*a.y + w21*b.y + w12*d.y + w22*e.y;
            r.z = w11*a.z + w21*b.z + w12*d.z + w22*e.z;
            r.w = w11*a.w + w21*b.w + w12*d.w + w22*e.w;
            *reinterpret_cast<f4v*>(orow + 3 + ch) = r;
        } else if (t < 243) {
            orow[t - 240] = coord[p*3 + (t-240)];
        }
    }
}

extern "C" void kernel_launch(void* const* d_in, const int* in_sizes, int n_in,
                              void* d_out, int out_size, void* d_ws, size_t ws_size,
                              hipStream_t stream) {
    const float* coord = (const float*)d_in[0];
    const float* f56   = (const float*)d_in[1];
    const float* f28   = (const float*)d_in[2];
    const float* f14   = (const float*)d_in[3];
    const float* f7    = (const float*)d_in[4];
    float* out = (float*)d_out;

    int n = in_sizes[0] / 3;  // 131072 points

    if (ws_size >= (size_t)NTOT * sizeof(_Float16)) {
        _Float16* ws = (_Float16*)d_ws;
        convert_feats_kernel<<<CONV_BLOCKS, 256, 0, stream>>>(f56, f28, f14, f7, ws);
        int grid = (n + 3) / 4;  // 32768 blocks, one point per wave
        GraphProjection_57483842289710_kernel<<<grid, 256, 0, stream>>>(coord, ws, out, n);
    } else {
        int grid = (n + 15) / 16;
        proj_f32_kernel<<<grid, 256, 0, stream>>>(coord, f56, f28, f14, f7, out, n);
    }
}

// Round 23
// 108.479 us; speedup vs baseline: 1.2814x; 1.2814x over previous
//
#include <hip/hip_runtime.h>

constexpr int PPB = 4;   // points per block (32768 blocks); NG=1 -> single buffer
constexpr int GRP = 4;   // points per LDS buffer (15408 B); ONE buffer = 15.4 KB
constexpr int N56 = 56*56*64;    // 200704
constexpr int N28 = 28*28*128;   // 100352
constexpr int N14 = 14*14*256;   //  50176
constexpr int N7  = 7*7*512;     //  25088
constexpr int NTOT = N56 + N28 + N14 + N7;       // 376320
constexpr int CONV_BLOCKS = (NTOT + 255) / 256;  // 1470

typedef float    f4v __attribute__((ext_vector_type(4)));
typedef _Float16 h4v __attribute__((ext_vector_type(4)));

// LDS-only barrier: drain LDS ops but leave nt stores / gathers in flight.
__device__ __forceinline__ void lds_barrier() {
    asm volatile("s_waitcnt lgkmcnt(0)" ::: "memory");
    __builtin_amdgcn_s_barrier();
    asm volatile("" ::: "memory");
}

// ---- fp32 features -> fp16 in d_ws ----
__global__ __launch_bounds__(256) void convert_feats_kernel(
    const float* __restrict__ f56, const float* __restrict__ f28,
    const float* __restrict__ f14, const float* __restrict__ f7,
    _Float16* __restrict__ ws)
{
    int idx = blockIdx.x * 256 + threadIdx.x;
    if (idx >= NTOT) return;
    float v;
    if (idx < N56)              v = f56[idx];
    else if (idx < N56+N28)     v = f28[idx - N56];
    else if (idx < N56+N28+N14) v = f14[idx - (N56+N28)];
    else                        v = f7[idx - (N56+N28+N14)];
    ws[idx] = (_Float16)v;
}

// compute GRP points' rows into the LDS buffer (this thread's channel quad)
__device__ __forceinline__ void compute_group(
    int pg, int n, int t, int ch,
    const float* __restrict__ coord,
    const _Float16* __restrict__ f, int C, int H, float inv,
    float* __restrict__ buf)
{
    #pragma unroll
    for (int k = 0; k < GRP; ++k) {
        const int p = pg + k;
        if (p >= n) break;

        const float X = coord[p * 3 + 0];
        const float Y = coord[p * 3 + 1];
        const float Z = coord[p * 3 + 2];

        const float rz = 1.0f / (-Z);
        float h = 250.0f * (-Y) * rz + 112.0f;
        float w = 250.0f * X  * rz + 112.0f;
        h = fminf(fmaxf(h, 0.0f), 223.0f);
        w = fminf(fmaxf(w, 0.0f), 223.0f);

        if (t < 240) {
            const float x = h * inv, y = w * inv;
            const float x1 = floorf(x), x2 = ceilf(x);
            const float y1 = floorf(y), y2 = ceilf(y);
            const int xi1 = min(max((int)x1, 0), H - 1);
            const int xi2 = min(max((int)x2, 0), H - 1);
            const int yi1 = min(max((int)y1, 0), H - 1);
            const int yi2 = min(max((int)y2, 0), H - 1);
            const float w11 = (x2 - x) * (y2 - y);
            const float w21 = (x - x1) * (y2 - y);
            const float w12 = (x2 - x) * (y - y1);
            const float w22 = (x - x1) * (y - y1);

            const int r1 = xi1 * H, r2 = xi2 * H;
            const h4v a = *reinterpret_cast<const h4v*>(f + (r1 + yi1) * C);
            const h4v b = *reinterpret_cast<const h4v*>(f + (r2 + yi1) * C);
            const h4v d = *reinterpret_cast<const h4v*>(f + (r1 + yi2) * C);
            const h4v e = *reinterpret_cast<const h4v*>(f + (r2 + yi2) * C);

            float* dst = buf + k * 963 + 3 + ch;
            dst[0] = w11*(float)a.x + w21*(float)b.x + w12*(float)d.x + w22*(float)e.x;
            dst[1] = w11*(float)a.y + w21*(float)b.y + w12*(float)d.y + w22*(float)e.y;
            dst[2] = w11*(float)a.z + w21*(float)b.z + w12*(float)d.z + w22*(float)e.z;
            dst[3] = w11*(float)a.w + w21*(float)b.w + w12*(float)d.w + w22*(float)e.w;
        } else if (t < 243) {
            buf[k * 963 + (t - 240)] = coord[p * 3 + (t - 240)];
        }
    }
}

// flush the buffer (GRP rows, 15408 B contiguous) as aligned nt float4 burst
__device__ __forceinline__ void flush_group(
    const float* __restrict__ buf, float* __restrict__ dst_base, int t)
{
    const f4v* __restrict__ s4 = reinterpret_cast<const f4v*>(buf);
    f4v* __restrict__ d4 = reinterpret_cast<f4v*>(dst_base);
    #pragma unroll
    for (int i = t; i < GRP * 963 / 4; i += 256)   // 963 float4s
        __builtin_nontemporal_store(s4[i], d4 + i);
}

// ---- hot kernel: single-buffer, compute -> barrier -> flush.
// __launch_bounds__(256, 8): force <=64 VGPR so all 8 LDS-permitted
// blocks/CU are actually resident (32 waves/CU, max TLP). ----
__global__ __launch_bounds__(256, 8) void GraphProjection_57483842289710_kernel(
    const float* __restrict__ coord,
    const _Float16* __restrict__ ws,
    float* __restrict__ out, int n)
{
    __shared__ float lds[GRP * 963];   // 15408 B -> 8 blocks/CU

    const int t = threadIdx.x;
    const int ch = 4 * t;
    const _Float16* f; int C, H; float inv;
    if (ch < 64)       { f = ws + ch;                     C = 64;  H = 56; inv = 0.25f;    }
    else if (ch < 192) { f = ws + N56 + (ch - 64);        C = 128; H = 28; inv = 0.125f;   }
    else if (ch < 448) { f = ws + N56+N28 + (ch - 192);   C = 256; H = 14; inv = 0.0625f;  }
    else               { f = ws + N56+N28+N14 + (ch-448); C = 512; H = 7;  inv = 0.03125f; }

    const int p0 = blockIdx.x * PPB;

    compute_group(p0, n, t, ch, coord, f, C, H, inv, lds);
    lds_barrier();
    flush_group(lds, out + (size_t)p0 * 963, t);
}

// ---- fp32 fallback (round-4 winner) if ws too small ----
__global__ __launch_bounds__(256) void proj_f32_kernel(
    const float* __restrict__ coord,
    const float* __restrict__ f56, const float* __restrict__ f28,
    const float* __restrict__ f14, const float* __restrict__ f7,
    float* __restrict__ out, int n)
{
    const int t = threadIdx.x;
    const int ch = 4 * t;
    const float* f; int C, H; float inv;
    if (ch < 64)       { f = f56 + ch;         C = 64;  H = 56; inv = 0.25f;    }
    else if (ch < 192) { f = f28 + (ch - 64);  C = 128; H = 28; inv = 0.125f;   }
    else if (ch < 448) { f = f14 + (ch - 192); C = 256; H = 14; inv = 0.0625f;  }
    else               { f = f7  + (ch - 448); C = 512; H = 7;  inv = 0.03125f; }
    const int p0 = blockIdx.x * 16, pend = min(p0 + 16, n);
    #pragma unroll 2
    for (int p = p0; p < pend; ++p) {
        float* __restrict__ orow = out + (size_t)p * 963;
        const float X = coord[p*3+0], Y = coord[p*3+1], Z = coord[p*3+2];
        const float rz = 1.0f / (-Z);
        float h = 250.0f * (-Y) * rz + 112.0f;
        float w = 250.0f * X  * rz + 112.0f;
        h = fminf(fmaxf(h, 0.0f), 223.0f);
        w = fminf(fmaxf(w, 0.0f), 223.0f);
        if (t < 240) {
            const float x = h * inv, y = w * inv;
            const float x1 = floorf(x), x2 = ceilf(x);
            const float y1 = floorf(y), y2 = ceilf(y);
            const int xi1 = min(max((int)x1, 0), H - 1);
            const int xi2 = min(max((int)x2, 0), H - 1);
            const int yi1 = min(max((int)y1, 0), H - 1);
            const int yi2 = min(max((int)y2, 0), H - 1);
            const float w11 = (x2-x)*(y2-y), w21 = (x-x1)*(y2-y);
            const float w12 = (x2-x)*(y-y1), w22 = (x-x1)*(y-y1);
            const int r1 = xi1*H, r2 = xi2*H;
            const float4 a = *reinterpret_cast<const float4*>(f + (r1+yi1)*C);
            const float4 b = *reinterpret_cast<const float4*>(f + (r2+yi1)*C);
            const float4 d = *reinterpret_cast<const float4*>(f + (r1+yi2)*C);
            const float4 e = *reinterpret_cast<const float4*>(f + (r2+yi2)*C);
            f4v r;
            r.x = w11*a.x + w21*b.x + w12*d.x + w22*e.x;
            r.y = w11*a.y + w21*b.y + w12*d.y + w22*e.y;
            r.z = w11*a.z + w21*b.z + w12*d.z + w22*e.z;
            r.w = w11*a.w + w21*b.w + w12*d.w + w22*e.w;
            *reinterpret_cast<f4v*>(orow + 3 + ch) = r;
        } else if (t < 243) {
            orow[t - 240] = coord[p*3 + (t-240)];
        }
    }
}

extern "C" void kernel_launch(void* const* d_in, const int* in_sizes, int n_in,
                              void* d_out, int out_size, void* d_ws, size_t ws_size,
                              hipStream_t stream) {
    const float* coord = (const float*)d_in[0];
    const float* f56   = (const float*)d_in[1];
    const float* f28   = (const float*)d_in[2];
    const float* f14   = (const float*)d_in[3];
    const float* f7    = (const float*)d_in[4];
    float* out = (float*)d_out;

    int n = in_sizes[0] / 3;  // 131072 points

    if (ws_size >= (size_t)NTOT * sizeof(_Float16)) {
        _Float16* ws = (_Float16*)d_ws;
        convert_feats_kernel<<<CONV_BLOCKS, 256, 0, stream>>>(f56, f28, f14, f7, ws);
        int grid = (n + PPB - 1) / PPB;  // 32768
        GraphProjection_57483842289710_kernel<<<grid, 256, 0, stream>>>(coord, ws, out, n);
    } else {
        int grid = (n + 15) / 16;
        proj_f32_kernel<<<grid, 256, 0, stream>>>(coord, f56, f28, f14, f7, out, n);
    }
}